// Round 6
// baseline (75.282 us; speedup 1.0000x reference)
//
#include <hip/hip_runtime.h>
#include <cstdint>
#include <cstddef>

#define NEG_SLOPE 0.2f

typedef __attribute__((ext_vector_type(8))) short bf16x8;
typedef __attribute__((ext_vector_type(4))) short s16x4;
typedef __attribute__((ext_vector_type(8))) unsigned short u16x8;
typedef __attribute__((ext_vector_type(4))) float f32x4;

__device__ __forceinline__ float leaky_f(float x) { return x >= 0.f ? x : NEG_SLOPE * x; }

__device__ __forceinline__ unsigned short f2bf(float f) {
    union { float f; uint32_t u; } v; v.f = f;
    return (unsigned short)((v.u + 0x7fffu + ((v.u >> 16) & 1u)) >> 16);
}
__device__ __forceinline__ float bf2f(unsigned short u) {
    union { uint32_t u; float f; } v; v.u = ((uint32_t)u) << 16; return v.f;
}
__device__ __forceinline__ u16x8 cvt8(float4 a, float4 b) {
    u16x8 o;
    o[0] = f2bf(a.x); o[1] = f2bf(a.y); o[2] = f2bf(a.z); o[3] = f2bf(a.w);
    o[4] = f2bf(b.x); o[5] = f2bf(b.y); o[6] = f2bf(b.z); o[7] = f2bf(b.w);
    return o;
}

// ==================== pack: weights -> fragment-ready bf16; cn2 ====================
// frag(step,f): 64 lanes x 8 bf16; lane elem j = W[f*16+(lane&15)][step*32+(lane>>4)*8+j]
__global__ __launch_bounds__(256)
void pack_kernel(const float* __restrict__ W1, const float* __restrict__ W2,
                 const float* __restrict__ W21, const float* __restrict__ cent,
                 unsigned short* __restrict__ pw1, unsigned short* __restrict__ pw2,
                 unsigned short* __restrict__ pw3, float* __restrict__ cn2g)
{
    const int bid = blockIdx.x, tid = threadIdx.x;
    if (bid < 36) {                       // 144 weight fragments, 4 per block
        const int sub = tid >> 6, lane = tid & 63, g = bid * 4 + sub;
        const int l15 = lane & 15, l4 = lane >> 4;
        const float* src; unsigned short* dst;
        if (g < 64) {        // W1: 8 steps x 8 frags, K=256
            int step = g >> 3, f = g & 7;
            src = W1 + (size_t)(f * 16 + l15) * 256 + step * 32 + l4 * 8;
            dst = pw1 + ((size_t)(step * 8 + f) * 64 + lane) * 8;
        } else if (g < 96) { // W2: 4 steps x 8 frags, K=128
            int gg = g - 64, step = gg >> 3, f = gg & 7;
            src = W2 + (size_t)(f * 16 + l15) * 128 + step * 32 + l4 * 8;
            dst = pw2 + ((size_t)(step * 8 + f) * 64 + lane) * 8;
        } else {             // [W21;cent]: 4 steps x 12 frags, K=128
            int gg = g - 96, step = gg / 12, f = gg % 12;
            int brow = f * 16 + l15;
            const float* base = (brow < 128) ? (W21 + (size_t)brow * 128)
                                             : (cent + (size_t)(brow - 128) * 128);
            src = base + step * 32 + l4 * 8;
            dst = pw3 + ((size_t)(step * 12 + f) * 64 + lane) * 8;
        }
        float4 a = *reinterpret_cast<const float4*>(src);
        float4 b = *reinterpret_cast<const float4*>(src + 4);
        *reinterpret_cast<u16x8*>(dst) = cvt8(a, b);
    } else {                              // cn2
        int r = tid >> 2, c0 = (tid & 3) * 32;
        const float* cr = cent + (size_t)r * 128 + c0;
        float s = 0.f;
#pragma unroll
        for (int q = 0; q < 8; q++) {
            float4 v = *reinterpret_cast<const float4*>(cr + q * 4);
            s += v.x * v.x + v.y * v.y + v.z * v.z + v.w * v.w;
        }
        s += __shfl_xor(s, 1); s += __shfl_xor(s, 2);
        if ((tid & 3) == 0) cn2g[r] = s;
    }
}

// ==================== fused GEMM chain: 16 rows/block, 4 waves (col-split) ====================
__global__ __launch_bounds__(256)
void fused_gemms(const float* __restrict__ x_node,
                 const unsigned short* __restrict__ pw1, const unsigned short* __restrict__ pw2,
                 const unsigned short* __restrict__ pw3,
                 const float* __restrict__ b1, const float* __restrict__ b2,
                 const float* __restrict__ cn2g,
                 float* __restrict__ h_out, unsigned short* __restrict__ hWb,
                 unsigned short* __restrict__ qtb, int N)
{
    __shared__ __align__(16) short As[16 * 264];   // x_node tile bf16
    __shared__ __align__(16) short Xs[16 * 136];   // x, then h (bf16)
    __shared__ float hn2s[4][16];

    const int tid = threadIdx.x, wave = tid >> 6, lane = tid & 63;
    const int l15 = lane & 15, l4 = lane >> 4;
    const int rowBlk = blockIdx.x * 16;

    // ---- Phase 0: stage x_node (16 x 256 f32 -> bf16 LDS) ----
    {
        int r = tid >> 4, c0 = (tid & 15) * 16;
        const float* src = x_node + (size_t)(rowBlk + r) * 256 + c0;
        float4 v0 = *reinterpret_cast<const float4*>(src);
        float4 v1 = *reinterpret_cast<const float4*>(src + 4);
        float4 v2 = *reinterpret_cast<const float4*>(src + 8);
        float4 v3 = *reinterpret_cast<const float4*>(src + 12);
        *reinterpret_cast<u16x8*>(&As[r * 264 + c0])     = cvt8(v0, v1);
        *reinterpret_cast<u16x8*>(&As[r * 264 + c0 + 8]) = cvt8(v2, v3);
    }
    __syncthreads();

    // ---- Phase 1: x = leaky(x_node @ W1^T + b1), K=256, 4 waves x 32 cols ----
    f32x4 a0{0.f,0.f,0.f,0.f}, a1{0.f,0.f,0.f,0.f}, a2{0.f,0.f,0.f,0.f};
    {
        const short* ap = &As[l15 * 264 + l4 * 8];
        const unsigned short* bp = pw1 + (size_t)(wave * 2) * 512 + lane * 8;
#pragma unroll
        for (int k = 0; k < 8; k++) {
            bf16x8 af = *reinterpret_cast<const bf16x8*>(ap + k * 32);
            bf16x8 bf0 = *reinterpret_cast<const bf16x8*>(bp + (size_t)k * 8 * 512);
            bf16x8 bf1 = *reinterpret_cast<const bf16x8*>(bp + (size_t)k * 8 * 512 + 512);
            a0 = __builtin_amdgcn_mfma_f32_16x16x32_bf16(af, bf0, a0, 0, 0, 0);
            a1 = __builtin_amdgcn_mfma_f32_16x16x32_bf16(af, bf1, a1, 0, 0, 0);
        }
        float bia = b1[wave * 32 + l15], bib = b1[wave * 32 + 16 + l15];
#pragma unroll
        for (int j = 0; j < 4; j++) {
            Xs[(l4 * 4 + j) * 136 + wave * 32 + l15]      = (short)f2bf(leaky_f(a0[j] + bia));
            Xs[(l4 * 4 + j) * 136 + wave * 32 + 16 + l15] = (short)f2bf(leaky_f(a1[j] + bib));
        }
    }
    __syncthreads();

    // ---- Phase 2: h = leaky(x @ W2^T + b2), K=128 ----
    a0 = f32x4{0.f,0.f,0.f,0.f}; a1 = f32x4{0.f,0.f,0.f,0.f};
    const short* xp = &Xs[l15 * 136 + l4 * 8];
    {
        const unsigned short* bp = pw2 + (size_t)(wave * 2) * 512 + lane * 8;
#pragma unroll
        for (int k = 0; k < 4; k++) {
            bf16x8 af = *reinterpret_cast<const bf16x8*>(xp + k * 32);
            bf16x8 bf0 = *reinterpret_cast<const bf16x8*>(bp + (size_t)k * 8 * 512);
            bf16x8 bf1 = *reinterpret_cast<const bf16x8*>(bp + (size_t)k * 8 * 512 + 512);
            a0 = __builtin_amdgcn_mfma_f32_16x16x32_bf16(af, bf0, a0, 0, 0, 0);
            a1 = __builtin_amdgcn_mfma_f32_16x16x32_bf16(af, bf1, a1, 0, 0, 0);
        }
    }
    float hv0[4], hv1[4], pn[4];
    {
        float bia = b2[wave * 32 + l15], bib = b2[wave * 32 + 16 + l15];
#pragma unroll
        for (int j = 0; j < 4; j++) {
            hv0[j] = leaky_f(a0[j] + bia);
            hv1[j] = leaky_f(a1[j] + bib);
            float s = hv0[j] * hv0[j] + hv1[j] * hv1[j];
            s += __shfl_xor(s, 1); s += __shfl_xor(s, 2);
            s += __shfl_xor(s, 4); s += __shfl_xor(s, 8);
            pn[j] = s;
        }
    }
    __syncthreads();   // all waves done reading Xs(x)
#pragma unroll
    for (int j = 0; j < 4; j++) {
        int gr = rowBlk + l4 * 4 + j;
        __builtin_nontemporal_store(hv0[j], &h_out[(size_t)gr * 128 + wave * 32 + l15]);
        __builtin_nontemporal_store(hv1[j], &h_out[(size_t)gr * 128 + wave * 32 + 16 + l15]);
        Xs[(l4 * 4 + j) * 136 + wave * 32 + l15]      = (short)f2bf(hv0[j]);
        Xs[(l4 * 4 + j) * 136 + wave * 32 + 16 + l15] = (short)f2bf(hv1[j]);
        if (l15 == 0) hn2s[wave][l4 * 4 + j] = pn[j];
    }
    __syncthreads();

    // ---- Phase 3: [hW | q] = h @ [W21;cent]^T, K=128, 192 cols in 4x48 ----
    a0 = f32x4{0.f,0.f,0.f,0.f}; a1 = f32x4{0.f,0.f,0.f,0.f}; a2 = f32x4{0.f,0.f,0.f,0.f};
    {
        const unsigned short* bp = pw3 + (size_t)(wave * 3) * 512 + lane * 8;
#pragma unroll
        for (int k = 0; k < 4; k++) {
            bf16x8 af = *reinterpret_cast<const bf16x8*>(xp + k * 32);
            bf16x8 bf0 = *reinterpret_cast<const bf16x8*>(bp + (size_t)k * 12 * 512);
            bf16x8 bf1 = *reinterpret_cast<const bf16x8*>(bp + (size_t)k * 12 * 512 + 512);
            bf16x8 bf2 = *reinterpret_cast<const bf16x8*>(bp + (size_t)k * 12 * 512 + 1024);
            a0 = __builtin_amdgcn_mfma_f32_16x16x32_bf16(af, bf0, a0, 0, 0, 0);
            a1 = __builtin_amdgcn_mfma_f32_16x16x32_bf16(af, bf1, a1, 0, 0, 0);
            a2 = __builtin_amdgcn_mfma_f32_16x16x32_bf16(af, bf2, a2, 0, 0, 0);
        }
    }
    {
        float hn2r[4];
#pragma unroll
        for (int j = 0; j < 4; j++)
            hn2r[j] = hn2s[0][l4 * 4 + j] + hn2s[1][l4 * 4 + j]
                    + hn2s[2][l4 * 4 + j] + hn2s[3][l4 * 4 + j];
        f32x4 av[3] = {a0, a1, a2};
#pragma unroll
        for (int ff = 0; ff < 3; ff++) {
            int col = wave * 48 + ff * 16 + l15;
            if (col < 128) {
#pragma unroll
                for (int j = 0; j < 4; j++) {
                    int gr = rowBlk + l4 * 4 + j;
                    hWb[(size_t)gr * 128 + col] = f2bf(av[ff][j]);
                }
            } else {
                int c2 = col - 128;
                float cn2v = cn2g[c2];
#pragma unroll
                for (int j = 0; j < 4; j++) {
                    int gr = rowBlk + l4 * 4 + j;
                    float q = 1.f / (1.f + cn2v + hn2r[j] - 2.f * av[ff][j]);
                    qtb[(size_t)gr * 64 + c2] = f2bf(q);
                }
            }
        }
    }
}

// ==================== per-node aggregation: one wave per node, MFMA PV ====================
// hs layout: 32 chunks of 128B; chunk (db*4+equad) holds rows e=equad*4..+3 x d=db*16..+15,
// row-major (rows of 32B). tr_read lane addr = chunk*128 + l15*8 (own 8B slot, m156/m162);
// lane l15 receives column l15 (d), elems j = rows (e). k>=16 lanes read a zeroed chunk.
__global__ __launch_bounds__(256)
void agg_kernel(const int* __restrict__ adj, const unsigned short* __restrict__ qtb,
                const unsigned short* __restrict__ hWb, const float* __restrict__ b21,
                const float* __restrict__ headConv, float* __restrict__ out1)
{
    __shared__ __align__(16) unsigned short qs[4][1024];   // [wave][e*64+hc]
    __shared__ __align__(16) unsigned short hs[4][2048];   // [wave] 32 chunks x 128B
    __shared__ __align__(16) unsigned short zb[64];        // shared 128B zero chunk

    const int tid = threadIdx.x;
    const int wv = tid >> 6, lane = tid & 63;
    const int eg = lane >> 4, l15 = lane & 15;
    const int n = blockIdx.x * 4 + wv;

    if (tid < 8) {
        u16x8 z{};
        *reinterpret_cast<u16x8*>(&zb[tid * 8]) = z;
    }

    int myadj = adj[n * 16 + l15];

    // stage q: 16 rows x 128B, linear
#pragma unroll
    for (int i = 0; i < 2; i++) {
        int row = i * 8 + (lane >> 3);
        int nb = __shfl(myadj, row);
        *reinterpret_cast<u16x8*>(&qs[wv][i * 512 + lane * 8]) =
            *reinterpret_cast<const u16x8*>(qtb + (size_t)nb * 64 + (lane & 7) * 8);
    }

    // stage hW into tr-tile chunks; per 16-lane group the write is 256B contiguous
    {
        const int equad = (eg & 1) * 2 + (l15 >> 3);
        const int e_st  = equad * 4 + ((l15 >> 1) & 3);
        const int nb    = __shfl(myadj, e_st);
        const int inner = ((l15 >> 1) & 3) * 32 + (l15 & 1) * 16;   // row*32 + half*16
#pragma unroll
        for (int i = 0; i < 4; i++) {
            int db  = i * 2 + (eg >> 1);
            int oct = db * 2 + (l15 & 1);
            int byteoff = (db * 4 + equad) * 128 + inner;
            *reinterpret_cast<u16x8*>(&hs[wv][byteoff >> 1]) =
                *reinterpret_cast<const u16x8*>(hWb + (size_t)nb * 128 + oct * 8);
        }
    }
    __syncthreads();

    // lane = hc: neighbor-sum + head-weighted logits + in-register softmax
    bf16x8 afrag;
    {
        float qv[16];
        float s = 0.f;
#pragma unroll
        for (int e = 0; e < 16; e++) { qv[e] = bf2f(qs[wv][e * 64 + lane]); s += qv[e]; }
        float rs = 1.f / s;
        float conv = headConv[eg];
        float wn[16], m = -1e30f;
#pragma unroll
        for (int e = 0; e < 16; e++) {
            float t = conv * qv[e] * rs;
            t += __shfl_xor(t, 16);
            t += __shfl_xor(t, 32);       // all lanes hold w_logit[c=l15][e]
            wn[e] = t;
            m = fmaxf(m, t);
        }
        float sum = 0.f;
#pragma unroll
        for (int e = 0; e < 16; e++) { wn[e] = __expf(wn[e] - m); sum += wn[e]; }
        float inv = 1.f / sum;
        bf16x8 w0{}, w1{}, wz{};
#pragma unroll
        for (int j = 0; j < 8; j++) {
            w0[j] = (short)f2bf(wn[j] * inv);
            w1[j] = (short)f2bf(wn[8 + j] * inv);
        }
        afrag = (eg == 0) ? w0 : (eg == 1) ? w1 : wz;   // A[c][k]: zero for k>=16
    }

    // tr-reads: per db, read1 = chunk(db, eg*2), read2 = chunk(db, eg*2+1); eg>=2 -> zero chunk
    s16x4 tr[16];
    {
        uint32_t rb  = (uint32_t)(uintptr_t)&hs[wv][0];
        uint32_t zba = (uint32_t)(uintptr_t)&zb[0];
        uint32_t base = (eg < 2) ? (rb + (uint32_t)(eg * 256 + l15 * 8))
                                 : (zba + (uint32_t)(l15 * 8));
        uint32_t step = (eg < 2) ? 512u : 0u;
        uint32_t d1   = (eg < 2) ? 128u : 0u;
#pragma unroll
        for (int db = 0; db < 8; db++) {
            uint32_t a0 = base + (uint32_t)db * step;
            uint32_t a1 = a0 + d1;
            asm volatile("ds_read_b64_tr_b16 %0, %1" : "=&v"(tr[2 * db])     : "v"(a0));
            asm volatile("ds_read_b64_tr_b16 %0, %1" : "=&v"(tr[2 * db + 1]) : "v"(a1));
        }
        asm volatile("s_waitcnt lgkmcnt(0)" ::: "memory");
        __builtin_amdgcn_sched_barrier(0);
    }

    // 8 MFMA: D[c][d] = sum_e w[c][e] * hW[e][d]
    f32x4 facc[8];
#pragma unroll
    for (int db = 0; db < 8; db++) {
        bf16x8 bfrag;
        s16x4 ra = tr[2 * db], rb2 = tr[2 * db + 1];
        bfrag[0] = ra[0]; bfrag[1] = ra[1]; bfrag[2] = ra[2]; bfrag[3] = ra[3];
        bfrag[4] = rb2[0]; bfrag[5] = rb2[1]; bfrag[6] = rb2[2]; bfrag[7] = rb2[3];
        f32x4 z{0.f, 0.f, 0.f, 0.f};
        facc[db] = __builtin_amdgcn_mfma_f32_16x16x32_bf16(afrag, bfrag, z, 0, 0, 0);
    }

    // epilogue: row c = eg*4+jj, col d = db*16+l15
    {
        float bb[8];
#pragma unroll
        for (int db = 0; db < 8; db++) bb[db] = b21[db * 16 + l15];
        float* obase = out1 + ((size_t)n * 16 + eg * 4) * 128 + l15;
#pragma unroll
        for (int jj = 0; jj < 4; jj++) {
            float* orow = obase + (size_t)jj * 128;
#pragma unroll
            for (int db = 0; db < 8; db++) {
                float v = leaky_f(facc[db][jj] + bb[db]);
                __builtin_nontemporal_store(v, orow + db * 16);
            }
        }
    }
}

extern "C" void kernel_launch(void* const* d_in, const int* in_sizes, int n_in,
                              void* d_out, int out_size, void* d_ws, size_t ws_size,
                              hipStream_t stream)
{
    const float* x_node   = (const float*)d_in[0];
    const int*   adj      = (const int*)  d_in[1];
    const float* W1       = (const float*)d_in[3];
    const float* b1       = (const float*)d_in[4];
    const float* W2       = (const float*)d_in[5];
    const float* b2       = (const float*)d_in[6];
    const float* W21      = (const float*)d_in[7];
    const float* b21      = (const float*)d_in[8];
    const float* cent     = (const float*)d_in[9];
    const float* headConv = (const float*)d_in[10];

    const int N = in_sizes[0] / 256;     // 20000

    float* h    = (float*)d_out;                 // h_prime [N][128]
    float* out1 = h + (size_t)N * 128;           // new_feat [N][16][128]

    unsigned short* hWb = (unsigned short*)d_ws;       // [N][128] bf16
    unsigned short* qtb = hWb + (size_t)N * 128;       // [N][64]  bf16
    unsigned short* pw1 = qtb + (size_t)N * 64;        // 32768
    unsigned short* pw2 = pw1 + 32768;                 // 16384
    unsigned short* pw3 = pw2 + 16384;                 // 24576
    float*          cn2g = (float*)(pw3 + 24576);      // [64]

    pack_kernel<<<37, 256, 0, stream>>>(W1, W2, W21, cent, pw1, pw2, pw3, cn2g);
    fused_gemms<<<N / 16, 256, 0, stream>>>(x_node, pw1, pw2, pw3, b1, b2, cn2g,
                                            h, hWb, qtb, N);
    agg_kernel<<<N / 4, 256, 0, stream>>>(adj, qtb, hWb, b21, headConv, out1);
}

// Round 7
// 73.827 us; speedup vs baseline: 1.0197x; 1.0197x over previous
//
#include <hip/hip_runtime.h>
#include <cstdint>
#include <cstddef>

#define NEG_SLOPE 0.2f

typedef __attribute__((ext_vector_type(8))) short bf16x8;
typedef __attribute__((ext_vector_type(8))) unsigned short u16x8;
typedef __attribute__((ext_vector_type(4))) float f32x4;

__device__ __forceinline__ float leaky_f(float x) { return x >= 0.f ? x : NEG_SLOPE * x; }

__device__ __forceinline__ unsigned short f2bf(float f) {
    union { float f; uint32_t u; } v; v.f = f;
    return (unsigned short)((v.u + 0x7fffu + ((v.u >> 16) & 1u)) >> 16);
}
__device__ __forceinline__ float bf2f(unsigned short u) {
    union { uint32_t u; float f; } v; v.u = ((uint32_t)u) << 16; return v.f;
}
__device__ __forceinline__ float bfhi(uint32_t w) {
    union { uint32_t u; float f; } v; v.u = w & 0xffff0000u; return v.f;
}
__device__ __forceinline__ float bflo(uint32_t w) {
    union { uint32_t u; float f; } v; v.u = w << 16; return v.f;
}
__device__ __forceinline__ u16x8 cvt8(float4 a, float4 b) {
    u16x8 o;
    o[0] = f2bf(a.x); o[1] = f2bf(a.y); o[2] = f2bf(a.z); o[3] = f2bf(a.w);
    o[4] = f2bf(b.x); o[5] = f2bf(b.y); o[6] = f2bf(b.z); o[7] = f2bf(b.w);
    return o;
}

// ==================== pack: weights -> fragment-ready bf16; cn2 ====================
// frag(step,f): 64 lanes x 8 bf16; lane elem j = W[f*16+(lane&15)][step*32+(lane>>4)*8+j]
__global__ __launch_bounds__(256)
void pack_kernel(const float* __restrict__ W1, const float* __restrict__ W2,
                 const float* __restrict__ W21, const float* __restrict__ cent,
                 unsigned short* __restrict__ pw1, unsigned short* __restrict__ pw2,
                 unsigned short* __restrict__ pw3, float* __restrict__ cn2g)
{
    const int bid = blockIdx.x, tid = threadIdx.x;
    if (bid < 36) {                       // 144 weight fragments, 4 per block
        const int sub = tid >> 6, lane = tid & 63, g = bid * 4 + sub;
        const int l15 = lane & 15, l4 = lane >> 4;
        const float* src; unsigned short* dst;
        if (g < 64) {        // W1: 8 steps x 8 frags, K=256
            int step = g >> 3, f = g & 7;
            src = W1 + (size_t)(f * 16 + l15) * 256 + step * 32 + l4 * 8;
            dst = pw1 + ((size_t)(step * 8 + f) * 64 + lane) * 8;
        } else if (g < 96) { // W2: 4 steps x 8 frags, K=128
            int gg = g - 64, step = gg >> 3, f = gg & 7;
            src = W2 + (size_t)(f * 16 + l15) * 128 + step * 32 + l4 * 8;
            dst = pw2 + ((size_t)(step * 8 + f) * 64 + lane) * 8;
        } else {             // [W21;cent]: 4 steps x 12 frags, K=128
            int gg = g - 96, step = gg / 12, f = gg % 12;
            int brow = f * 16 + l15;
            const float* base = (brow < 128) ? (W21 + (size_t)brow * 128)
                                             : (cent + (size_t)(brow - 128) * 128);
            src = base + step * 32 + l4 * 8;
            dst = pw3 + ((size_t)(step * 12 + f) * 64 + lane) * 8;
        }
        float4 a = *reinterpret_cast<const float4*>(src);
        float4 b = *reinterpret_cast<const float4*>(src + 4);
        *reinterpret_cast<u16x8*>(dst) = cvt8(a, b);
    } else {                              // cn2
        int r = tid >> 2, c0 = (tid & 3) * 32;
        const float* cr = cent + (size_t)r * 128 + c0;
        float s = 0.f;
#pragma unroll
        for (int q = 0; q < 8; q++) {
            float4 v = *reinterpret_cast<const float4*>(cr + q * 4);
            s += v.x * v.x + v.y * v.y + v.z * v.z + v.w * v.w;
        }
        s += __shfl_xor(s, 1); s += __shfl_xor(s, 2);
        if ((tid & 3) == 0) cn2g[r] = s;
    }
}

// ==================== fused GEMM chain: 16 rows/block, 4 waves (col-split) ====================
// Phase 1 A-fragments come straight from global x_node (32B/lane per k, L1-shared across
// waves) — no LDS staging pass, no extra barrier. Phases 2/3 read h/x from Xs.
__global__ __launch_bounds__(256)
void fused_gemms(const float* __restrict__ x_node,
                 const unsigned short* __restrict__ pw1, const unsigned short* __restrict__ pw2,
                 const unsigned short* __restrict__ pw3,
                 const float* __restrict__ b1, const float* __restrict__ b2,
                 const float* __restrict__ cn2g,
                 float* __restrict__ h_out, unsigned short* __restrict__ hWb,
                 unsigned short* __restrict__ qtb, int N)
{
    __shared__ __align__(16) short Xs[16 * 136];   // x, then h (bf16)
    __shared__ float hn2s[4][16];

    const int tid = threadIdx.x, wave = tid >> 6, lane = tid & 63;
    const int l15 = lane & 15, l4 = lane >> 4;
    const int rowBlk = blockIdx.x * 16;

    // ---- Phase 1: x = leaky(x_node @ W1^T + b1), K=256, 4 waves x 32 cols ----
    f32x4 a0{0.f,0.f,0.f,0.f}, a1{0.f,0.f,0.f,0.f}, a2{0.f,0.f,0.f,0.f};
    {
        const float* ap = x_node + (size_t)(rowBlk + l15) * 256 + l4 * 8;
        const unsigned short* bp = pw1 + (size_t)(wave * 2) * 512 + lane * 8;
#pragma unroll
        for (int k = 0; k < 8; k++) {
            float4 va = *reinterpret_cast<const float4*>(ap + k * 32);
            float4 vb = *reinterpret_cast<const float4*>(ap + k * 32 + 4);
            u16x8 au = cvt8(va, vb);
            bf16x8 af = *reinterpret_cast<const bf16x8*>(&au);
            bf16x8 bf0 = *reinterpret_cast<const bf16x8*>(bp + (size_t)k * 8 * 512);
            bf16x8 bf1 = *reinterpret_cast<const bf16x8*>(bp + (size_t)k * 8 * 512 + 512);
            a0 = __builtin_amdgcn_mfma_f32_16x16x32_bf16(af, bf0, a0, 0, 0, 0);
            a1 = __builtin_amdgcn_mfma_f32_16x16x32_bf16(af, bf1, a1, 0, 0, 0);
        }
        float bia = b1[wave * 32 + l15], bib = b1[wave * 32 + 16 + l15];
#pragma unroll
        for (int j = 0; j < 4; j++) {
            Xs[(l4 * 4 + j) * 136 + wave * 32 + l15]      = (short)f2bf(leaky_f(a0[j] + bia));
            Xs[(l4 * 4 + j) * 136 + wave * 32 + 16 + l15] = (short)f2bf(leaky_f(a1[j] + bib));
        }
    }
    __syncthreads();

    // ---- Phase 2: h = leaky(x @ W2^T + b2), K=128 ----
    a0 = f32x4{0.f,0.f,0.f,0.f}; a1 = f32x4{0.f,0.f,0.f,0.f};
    const short* xp = &Xs[l15 * 136 + l4 * 8];
    {
        const unsigned short* bp = pw2 + (size_t)(wave * 2) * 512 + lane * 8;
#pragma unroll
        for (int k = 0; k < 4; k++) {
            bf16x8 af = *reinterpret_cast<const bf16x8*>(xp + k * 32);
            bf16x8 bf0 = *reinterpret_cast<const bf16x8*>(bp + (size_t)k * 8 * 512);
            bf16x8 bf1 = *reinterpret_cast<const bf16x8*>(bp + (size_t)k * 8 * 512 + 512);
            a0 = __builtin_amdgcn_mfma_f32_16x16x32_bf16(af, bf0, a0, 0, 0, 0);
            a1 = __builtin_amdgcn_mfma_f32_16x16x32_bf16(af, bf1, a1, 0, 0, 0);
        }
    }
    float hv0[4], hv1[4], pn[4];
    {
        float bia = b2[wave * 32 + l15], bib = b2[wave * 32 + 16 + l15];
#pragma unroll
        for (int j = 0; j < 4; j++) {
            hv0[j] = leaky_f(a0[j] + bia);
            hv1[j] = leaky_f(a1[j] + bib);
            float s = hv0[j] * hv0[j] + hv1[j] * hv1[j];
            s += __shfl_xor(s, 1); s += __shfl_xor(s, 2);
            s += __shfl_xor(s, 4); s += __shfl_xor(s, 8);
            pn[j] = s;
        }
    }
    __syncthreads();   // all waves done reading Xs(x)
#pragma unroll
    for (int j = 0; j < 4; j++) {
        int gr = rowBlk + l4 * 4 + j;
        __builtin_nontemporal_store(hv0[j], &h_out[(size_t)gr * 128 + wave * 32 + l15]);
        __builtin_nontemporal_store(hv1[j], &h_out[(size_t)gr * 128 + wave * 32 + 16 + l15]);
        Xs[(l4 * 4 + j) * 136 + wave * 32 + l15]      = (short)f2bf(hv0[j]);
        Xs[(l4 * 4 + j) * 136 + wave * 32 + 16 + l15] = (short)f2bf(hv1[j]);
        if (l15 == 0) hn2s[wave][l4 * 4 + j] = pn[j];
    }
    __syncthreads();

    // ---- Phase 3: [hW | q] = h @ [W21;cent]^T, K=128, 192 cols in 4x48 ----
    a0 = f32x4{0.f,0.f,0.f,0.f}; a1 = f32x4{0.f,0.f,0.f,0.f}; a2 = f32x4{0.f,0.f,0.f,0.f};
    {
        const unsigned short* bp = pw3 + (size_t)(wave * 3) * 512 + lane * 8;
#pragma unroll
        for (int k = 0; k < 4; k++) {
            bf16x8 af = *reinterpret_cast<const bf16x8*>(xp + k * 32);
            bf16x8 bf0 = *reinterpret_cast<const bf16x8*>(bp + (size_t)k * 12 * 512);
            bf16x8 bf1 = *reinterpret_cast<const bf16x8*>(bp + (size_t)k * 12 * 512 + 512);
            bf16x8 bf2 = *reinterpret_cast<const bf16x8*>(bp + (size_t)k * 12 * 512 + 1024);
            a0 = __builtin_amdgcn_mfma_f32_16x16x32_bf16(af, bf0, a0, 0, 0, 0);
            a1 = __builtin_amdgcn_mfma_f32_16x16x32_bf16(af, bf1, a1, 0, 0, 0);
            a2 = __builtin_amdgcn_mfma_f32_16x16x32_bf16(af, bf2, a2, 0, 0, 0);
        }
    }
    {
        float hn2r[4];
#pragma unroll
        for (int j = 0; j < 4; j++)
            hn2r[j] = hn2s[0][l4 * 4 + j] + hn2s[1][l4 * 4 + j]
                    + hn2s[2][l4 * 4 + j] + hn2s[3][l4 * 4 + j];
        f32x4 av[3] = {a0, a1, a2};
#pragma unroll
        for (int ff = 0; ff < 3; ff++) {
            int col = wave * 48 + ff * 16 + l15;
            if (col < 128) {
#pragma unroll
                for (int j = 0; j < 4; j++) {
                    int gr = rowBlk + l4 * 4 + j;
                    hWb[(size_t)gr * 128 + col] = f2bf(av[ff][j]);
                }
            } else {
                int c2 = col - 128;
                float cn2v = cn2g[c2];
#pragma unroll
                for (int j = 0; j < 4; j++) {
                    int gr = rowBlk + l4 * 4 + j;
                    float q = 1.f / (1.f + cn2v + hn2r[j] - 2.f * av[ff][j]);
                    qtb[(size_t)gr * 64 + c2] = f2bf(q);
                }
            }
        }
    }
}

// ==================== per-node aggregation: one wave per node, bf16 tables (R4-proven) ====================
__global__ __launch_bounds__(256)
void agg_kernel(const int* __restrict__ adj, const unsigned short* __restrict__ qtb,
                const unsigned short* __restrict__ hWb, const float* __restrict__ b21,
                const float* __restrict__ headConv, float* __restrict__ out1)
{
    __shared__ __align__(16) unsigned short qs[4][16 * 64];
    __shared__ __align__(16) unsigned short hs[4][16 * 128];
    __shared__ float wbuf[4][16][16];

    const int wv = threadIdx.x >> 6, lane = threadIdx.x & 63;
    const int n = blockIdx.x * 4 + wv;

    int myadj = adj[n * 16 + (lane & 15)];

    // stage q (16 rows x 128B) and hW (16 rows x 256B), linear LDS, conflict-free
#pragma unroll
    for (int i = 0; i < 2; i++) {
        int row = i * 8 + (lane >> 3);
        int nb = __shfl(myadj, row);
        *reinterpret_cast<u16x8*>(&qs[wv][i * 512 + lane * 8]) =
            *reinterpret_cast<const u16x8*>(qtb + (size_t)nb * 64 + (lane & 7) * 8);
    }
#pragma unroll
    for (int i = 0; i < 4; i++) {
        int row = i * 4 + (lane >> 4);
        int nb = __shfl(myadj, row);
        *reinterpret_cast<u16x8*>(&hs[wv][i * 512 + lane * 8]) =
            *reinterpret_cast<const u16x8*>(hWb + (size_t)nb * 128 + (lane & 15) * 8);
    }
    __syncthreads();

    // lane = hc: neighbor-sum + head-weighted logits + in-register softmax
    {
        float qv[16];
        float s = 0.f;
#pragma unroll
        for (int e = 0; e < 16; e++) { qv[e] = bf2f(qs[wv][e * 64 + lane]); s += qv[e]; }
        float rs = 1.f / s;
        float conv = headConv[lane >> 4];
        float wn[16], m = -1e30f;
#pragma unroll
        for (int e = 0; e < 16; e++) {
            float t = conv * qv[e] * rs;
            t += __shfl_xor(t, 16);
            t += __shfl_xor(t, 32);       // all lanes now hold w_logit[c][e]
            wn[e] = t;
            m = fmaxf(m, t);
        }
        float sum = 0.f;
#pragma unroll
        for (int e = 0; e < 16; e++) { wn[e] = __expf(wn[e] - m); sum += wn[e]; }
        float inv = 1.f / sum;
        const int c = lane & 15, eg = lane >> 4;
#pragma unroll
        for (int j = 0; j < 4; j++) wbuf[wv][eg * 4 + j][c] = wn[eg * 4 + j] * inv;
    }
    __syncthreads();

    // out tile: lane (cg,dg) covers c = cg*4+jc, d = dg*4..+3 and +64..+67
    {
        const int dg = lane & 15, cg = lane >> 4, d0 = dg * 4;
        float bv[8];
        *reinterpret_cast<float4*>(bv)     = *reinterpret_cast<const float4*>(b21 + d0);
        *reinterpret_cast<float4*>(bv + 4) = *reinterpret_cast<const float4*>(b21 + d0 + 64);
        float acc[4][8];
#pragma unroll
        for (int jc = 0; jc < 4; jc++)
#pragma unroll
            for (int j = 0; j < 8; j++) acc[jc][j] = bv[j];

#pragma unroll
        for (int e = 0; e < 16; e++) {
            uint2 wlo = *reinterpret_cast<const uint2*>(&hs[wv][e * 128 + d0]);
            uint2 whi = *reinterpret_cast<const uint2*>(&hs[wv][e * 128 + 64 + d0]);
            float hv[8];
            hv[0] = bflo(wlo.x); hv[1] = bfhi(wlo.x); hv[2] = bflo(wlo.y); hv[3] = bfhi(wlo.y);
            hv[4] = bflo(whi.x); hv[5] = bfhi(whi.x); hv[6] = bflo(whi.y); hv[7] = bfhi(whi.y);
#pragma unroll
            for (int jc = 0; jc < 4; jc++) {
                float w = wbuf[wv][e][cg * 4 + jc];
#pragma unroll
                for (int j = 0; j < 8; j++) acc[jc][j] = fmaf(w, hv[j], acc[jc][j]);
            }
        }
#pragma unroll
        for (int jc = 0; jc < 4; jc++) {
            f32x4 lo, hi;
#pragma unroll
            for (int j = 0; j < 4; j++) { lo[j] = leaky_f(acc[jc][j]); hi[j] = leaky_f(acc[jc][j + 4]); }
            float* dst = out1 + ((size_t)(n * 16 + cg * 4 + jc)) * 128;
            __builtin_nontemporal_store(lo, reinterpret_cast<f32x4*>(dst + d0));
            __builtin_nontemporal_store(hi, reinterpret_cast<f32x4*>(dst + d0 + 64));
        }
    }
}

extern "C" void kernel_launch(void* const* d_in, const int* in_sizes, int n_in,
                              void* d_out, int out_size, void* d_ws, size_t ws_size,
                              hipStream_t stream)
{
    const float* x_node   = (const float*)d_in[0];
    const int*   adj      = (const int*)  d_in[1];
    const float* W1       = (const float*)d_in[3];
    const float* b1       = (const float*)d_in[4];
    const float* W2       = (const float*)d_in[5];
    const float* b2       = (const float*)d_in[6];
    const float* W21      = (const float*)d_in[7];
    const float* b21      = (const float*)d_in[8];
    const float* cent     = (const float*)d_in[9];
    const float* headConv = (const float*)d_in[10];

    const int N = in_sizes[0] / 256;     // 20000

    float* h    = (float*)d_out;                 // h_prime [N][128]
    float* out1 = h + (size_t)N * 128;           // new_feat [N][16][128]

    unsigned short* hWb = (unsigned short*)d_ws;       // [N][128] bf16
    unsigned short* qtb = hWb + (size_t)N * 128;       // [N][64]  bf16
    unsigned short* pw1 = qtb + (size_t)N * 64;        // 32768
    unsigned short* pw2 = pw1 + 32768;                 // 16384
    unsigned short* pw3 = pw2 + 16384;                 // 24576
    float*          cn2g = (float*)(pw3 + 24576);      // [64]

    pack_kernel<<<37, 256, 0, stream>>>(W1, W2, W21, cent, pw1, pw2, pw3, cn2g);
    fused_gemms<<<N / 16, 256, 0, stream>>>(x_node, pw1, pw2, pw3, b1, b2, cn2g,
                                            h, hWb, qtb, N);
    agg_kernel<<<N / 4, 256, 0, stream>>>(adj, qtb, hWb, b21, headConv, out1);
}

// Round 9
// 68.582 us; speedup vs baseline: 1.0977x; 1.0765x over previous
//
#include <hip/hip_runtime.h>
#include <cstdint>
#include <cstddef>

#define NEG_SLOPE 0.2f

typedef __attribute__((ext_vector_type(8))) short bf16x8;
typedef __attribute__((ext_vector_type(8))) unsigned short u16x8;
typedef __attribute__((ext_vector_type(4))) unsigned short u16x4;
typedef __attribute__((ext_vector_type(4))) float f32x4;

__device__ __forceinline__ float leaky_f(float x) { return x >= 0.f ? x : NEG_SLOPE * x; }

__device__ __forceinline__ unsigned short f2bf(float f) {
    union { float f; uint32_t u; } v; v.f = f;
    return (unsigned short)((v.u + 0x7fffu + ((v.u >> 16) & 1u)) >> 16);
}
__device__ __forceinline__ float bf2f(unsigned short u) {
    union { uint32_t u; float f; } v; v.u = ((uint32_t)u) << 16; return v.f;
}
__device__ __forceinline__ float bfhi(uint32_t w) {
    union { uint32_t u; float f; } v; v.u = w & 0xffff0000u; return v.f;
}
__device__ __forceinline__ float bflo(uint32_t w) {
    union { uint32_t u; float f; } v; v.u = w << 16; return v.f;
}
__device__ __forceinline__ u16x8 cvt8(float4 a, float4 b) {
    u16x8 o;
    o[0] = f2bf(a.x); o[1] = f2bf(a.y); o[2] = f2bf(a.z); o[3] = f2bf(a.w);
    o[4] = f2bf(b.x); o[5] = f2bf(b.y); o[6] = f2bf(b.z); o[7] = f2bf(b.w);
    return o;
}

// ==================== pack: weights -> fragment-ready bf16; x_node -> bf16; cn2 ====================
// frag(step,f): 64 lanes x 8 bf16; lane elem j = W[f*16+(lane&15)][step*32+(lane>>4)*8+j]
__global__ __launch_bounds__(256)
void pack_kernel(const float* __restrict__ x_node, const float* __restrict__ W1,
                 const float* __restrict__ W2, const float* __restrict__ W21,
                 const float* __restrict__ cent,
                 unsigned short* __restrict__ xb, unsigned short* __restrict__ pw1,
                 unsigned short* __restrict__ pw2, unsigned short* __restrict__ pw3,
                 float* __restrict__ cn2g, int N)
{
    const int bid = blockIdx.x, tid = threadIdx.x;
    if (bid < 36) {                       // 144 weight fragments, 4 per block
        const int sub = tid >> 6, lane = tid & 63, g = bid * 4 + sub;
        const int l15 = lane & 15, l4 = lane >> 4;
        const float* src; unsigned short* dst;
        if (g < 64) {        // W1: 8 steps x 8 frags, K=256
            int step = g >> 3, f = g & 7;
            src = W1 + (size_t)(f * 16 + l15) * 256 + step * 32 + l4 * 8;
            dst = pw1 + ((size_t)(step * 8 + f) * 64 + lane) * 8;
        } else if (g < 96) { // W2: 4 steps x 8 frags, K=128
            int gg = g - 64, step = gg >> 3, f = gg & 7;
            src = W2 + (size_t)(f * 16 + l15) * 128 + step * 32 + l4 * 8;
            dst = pw2 + ((size_t)(step * 8 + f) * 64 + lane) * 8;
        } else {             // [W21;cent]: 4 steps x 12 frags, K=128
            int gg = g - 96, step = gg / 12, f = gg % 12;
            int brow = f * 16 + l15;
            const float* base = (brow < 128) ? (W21 + (size_t)brow * 128)
                                             : (cent + (size_t)(brow - 128) * 128);
            src = base + step * 32 + l4 * 8;
            dst = pw3 + ((size_t)(step * 12 + f) * 64 + lane) * 8;
        }
        float4 a = *reinterpret_cast<const float4*>(src);
        float4 b = *reinterpret_cast<const float4*>(src + 4);
        *reinterpret_cast<u16x8*>(dst) = cvt8(a, b);
    } else if (bid == 36) {               // cn2
        int r = tid >> 2, c0 = (tid & 3) * 32;
        const float* cr = cent + (size_t)r * 128 + c0;
        float s = 0.f;
#pragma unroll
        for (int q = 0; q < 8; q++) {
            float4 v = *reinterpret_cast<const float4*>(cr + q * 4);
            s += v.x * v.x + v.y * v.y + v.z * v.z + v.w * v.w;
        }
        s += __shfl_xor(s, 1); s += __shfl_xor(s, 2);
        if ((tid & 3) == 0) cn2g[r] = s;
    } else {                              // x_node -> bf16, 4096 elems/block
        size_t base = (size_t)(bid - 37) * 4096 + (size_t)tid * 16;
        float4 v0 = *reinterpret_cast<const float4*>(x_node + base);
        float4 v1 = *reinterpret_cast<const float4*>(x_node + base + 4);
        float4 v2 = *reinterpret_cast<const float4*>(x_node + base + 8);
        float4 v3 = *reinterpret_cast<const float4*>(x_node + base + 12);
        *reinterpret_cast<u16x8*>(xb + base)     = cvt8(v0, v1);
        *reinterpret_cast<u16x8*>(xb + base + 8) = cvt8(v2, v3);
    }
}

// ==================== fused GEMM chain: 16 rows/block, 4 waves (col-split) ====================
// B fragments load straight from packed global; A from xb / Xs LDS.
// Epilogues bounce through LDS so every global store is a coalesced vector store.
// Barrier order: P1w -> S -> P2r -> S -> w(h) -> S -> P3r + h_out -> S -> hW/qt stores.
__global__ __launch_bounds__(256)
void fused_gemms(const unsigned short* __restrict__ xb,
                 const unsigned short* __restrict__ pw1, const unsigned short* __restrict__ pw2,
                 const unsigned short* __restrict__ pw3,
                 const float* __restrict__ b1, const float* __restrict__ b2,
                 const float* __restrict__ cn2g,
                 float* __restrict__ h_out, unsigned short* __restrict__ hWb,
                 unsigned short* __restrict__ qtb, int N)
{
    __shared__ __align__(16) short Xs[16 * 136];       // x, then h (bf16)
    __shared__ __align__(16) float hf32[16 * 132];     // h f32 bounce (pad: 2-way banks)
    __shared__ __align__(16) unsigned short hWs[16 * 136];  // hW bf16 bounce
    __shared__ __align__(16) unsigned short qts[16 * 72];   // qt bf16 bounce
    __shared__ float hn2s[4][16];

    const int tid = threadIdx.x, wave = tid >> 6, lane = tid & 63;
    const int l15 = lane & 15, l4 = lane >> 4;
    const int rowBlk = blockIdx.x * 16;

    // ---- Phase 1: x = leaky(x_node @ W1^T + b1), K=256, 4 waves x 32 cols ----
    f32x4 a0{0.f,0.f,0.f,0.f}, a1{0.f,0.f,0.f,0.f}, a2{0.f,0.f,0.f,0.f};
    {
        const unsigned short* ap = xb + (size_t)(rowBlk + l15) * 256 + l4 * 8;
        const unsigned short* bp = pw1 + (size_t)(wave * 2) * 512 + lane * 8;
#pragma unroll
        for (int k = 0; k < 8; k++) {
            bf16x8 af = *reinterpret_cast<const bf16x8*>(ap + k * 32);
            bf16x8 bf0 = *reinterpret_cast<const bf16x8*>(bp + (size_t)k * 8 * 512);
            bf16x8 bf1 = *reinterpret_cast<const bf16x8*>(bp + (size_t)k * 8 * 512 + 512);
            a0 = __builtin_amdgcn_mfma_f32_16x16x32_bf16(af, bf0, a0, 0, 0, 0);
            a1 = __builtin_amdgcn_mfma_f32_16x16x32_bf16(af, bf1, a1, 0, 0, 0);
        }
        float bia = b1[wave * 32 + l15], bib = b1[wave * 32 + 16 + l15];
#pragma unroll
        for (int j = 0; j < 4; j++) {
            Xs[(l4 * 4 + j) * 136 + wave * 32 + l15]      = (short)f2bf(leaky_f(a0[j] + bia));
            Xs[(l4 * 4 + j) * 136 + wave * 32 + 16 + l15] = (short)f2bf(leaky_f(a1[j] + bib));
        }
    }
    __syncthreads();

    // ---- Phase 2: h = leaky(x @ W2^T + b2), K=128 ----
    a0 = f32x4{0.f,0.f,0.f,0.f}; a1 = f32x4{0.f,0.f,0.f,0.f};
    const short* xp = &Xs[l15 * 136 + l4 * 8];
    {
        const unsigned short* bp = pw2 + (size_t)(wave * 2) * 512 + lane * 8;
#pragma unroll
        for (int k = 0; k < 4; k++) {
            bf16x8 af = *reinterpret_cast<const bf16x8*>(xp + k * 32);
            bf16x8 bf0 = *reinterpret_cast<const bf16x8*>(bp + (size_t)k * 8 * 512);
            bf16x8 bf1 = *reinterpret_cast<const bf16x8*>(bp + (size_t)k * 8 * 512 + 512);
            a0 = __builtin_amdgcn_mfma_f32_16x16x32_bf16(af, bf0, a0, 0, 0, 0);
            a1 = __builtin_amdgcn_mfma_f32_16x16x32_bf16(af, bf1, a1, 0, 0, 0);
        }
    }
    float hv0[4], hv1[4], pn[4];
    {
        float bia = b2[wave * 32 + l15], bib = b2[wave * 32 + 16 + l15];
#pragma unroll
        for (int j = 0; j < 4; j++) {
            hv0[j] = leaky_f(a0[j] + bia);
            hv1[j] = leaky_f(a1[j] + bib);
            float s = hv0[j] * hv0[j] + hv1[j] * hv1[j];
            s += __shfl_xor(s, 1); s += __shfl_xor(s, 2);
            s += __shfl_xor(s, 4); s += __shfl_xor(s, 8);
            pn[j] = s;
        }
    }
    __syncthreads();   // all waves done reading Xs(x); h still in registers

    // write h -> LDS (bf16 for P3, f32 for the coalesced store) + hn2 partials
#pragma unroll
    for (int j = 0; j < 4; j++) {
        int r = l4 * 4 + j;
        hf32[r * 132 + wave * 32 + l15]      = hv0[j];
        hf32[r * 132 + wave * 32 + 16 + l15] = hv1[j];
        Xs[r * 136 + wave * 32 + l15]      = (short)f2bf(hv0[j]);
        Xs[r * 136 + wave * 32 + 16 + l15] = (short)f2bf(hv1[j]);
        if (l15 == 0) hn2s[wave][r] = pn[j];
    }
    __syncthreads();   // h ready in LDS

    // ---- coalesced h_out store: 256 threads x 32B ----
    {
        int r = tid >> 4, c0 = (tid & 15) * 8;
        f32x4 v0 = *reinterpret_cast<const f32x4*>(&hf32[r * 132 + c0]);
        f32x4 v1 = *reinterpret_cast<const f32x4*>(&hf32[r * 132 + c0 + 4]);
        float* dst = h_out + (size_t)(rowBlk + r) * 128 + c0;
        __builtin_nontemporal_store(v0, reinterpret_cast<f32x4*>(dst));
        __builtin_nontemporal_store(v1, reinterpret_cast<f32x4*>(dst + 4));
    }

    // ---- Phase 3: [hW | q] = h @ [W21;cent]^T, K=128, 192 cols in 4x48 ----
    a0 = f32x4{0.f,0.f,0.f,0.f}; a1 = f32x4{0.f,0.f,0.f,0.f}; a2 = f32x4{0.f,0.f,0.f,0.f};
    {
        const unsigned short* bp = pw3 + (size_t)(wave * 3) * 512 + lane * 8;
#pragma unroll
        for (int k = 0; k < 4; k++) {
            bf16x8 af = *reinterpret_cast<const bf16x8*>(xp + k * 32);
            bf16x8 bf0 = *reinterpret_cast<const bf16x8*>(bp + (size_t)k * 12 * 512);
            bf16x8 bf1 = *reinterpret_cast<const bf16x8*>(bp + (size_t)k * 12 * 512 + 512);
            bf16x8 bf2 = *reinterpret_cast<const bf16x8*>(bp + (size_t)k * 12 * 512 + 1024);
            a0 = __builtin_amdgcn_mfma_f32_16x16x32_bf16(af, bf0, a0, 0, 0, 0);
            a1 = __builtin_amdgcn_mfma_f32_16x16x32_bf16(af, bf1, a1, 0, 0, 0);
            a2 = __builtin_amdgcn_mfma_f32_16x16x32_bf16(af, bf2, a2, 0, 0, 0);
        }
    }
    {
        float hn2r[4];
#pragma unroll
        for (int j = 0; j < 4; j++)
            hn2r[j] = hn2s[0][l4 * 4 + j] + hn2s[1][l4 * 4 + j]
                    + hn2s[2][l4 * 4 + j] + hn2s[3][l4 * 4 + j];
        f32x4 av[3] = {a0, a1, a2};
#pragma unroll
        for (int ff = 0; ff < 3; ff++) {
            int col = wave * 48 + ff * 16 + l15;
            if (col < 128) {
#pragma unroll
                for (int j = 0; j < 4; j++)
                    hWs[(l4 * 4 + j) * 136 + col] = f2bf(av[ff][j]);
            } else {
                int c2 = col - 128;
                float cn2v = cn2g[c2];
#pragma unroll
                for (int j = 0; j < 4; j++) {
                    float q = 1.f / (1.f + cn2v + hn2r[j] - 2.f * av[ff][j]);
                    qts[(l4 * 4 + j) * 72 + c2] = f2bf(q);
                }
            }
        }
    }
    __syncthreads();

    // ---- coalesced hWb (16B/thread) + qtb (8B/thread) stores, cached (agg re-reads) ----
    {
        int r = tid >> 4, c0 = (tid & 15) * 8;
        *reinterpret_cast<u16x8*>(hWb + (size_t)(rowBlk + r) * 128 + c0) =
            *reinterpret_cast<const u16x8*>(&hWs[r * 136 + c0]);
        int cq = (tid & 15) * 4;
        *reinterpret_cast<u16x4*>(qtb + (size_t)(rowBlk + r) * 64 + cq) =
            *reinterpret_cast<const u16x4*>(&qts[r * 72 + cq]);
    }
}

// ==================== per-node aggregation: one wave per node, bf16 tables (R4-proven) ====================
__global__ __launch_bounds__(256)
void agg_kernel(const int* __restrict__ adj, const unsigned short* __restrict__ qtb,
                const unsigned short* __restrict__ hWb, const float* __restrict__ b21,
                const float* __restrict__ headConv, float* __restrict__ out1)
{
    __shared__ __align__(16) unsigned short qs[4][16 * 64];
    __shared__ __align__(16) unsigned short hs[4][16 * 128];
    __shared__ float wbuf[4][16][16];

    const int wv = threadIdx.x >> 6, lane = threadIdx.x & 63;
    const int n = blockIdx.x * 4 + wv;

    int myadj = adj[n * 16 + (lane & 15)];

    // stage q (16 rows x 128B) and hW (16 rows x 256B), linear LDS, conflict-free
#pragma unroll
    for (int i = 0; i < 2; i++) {
        int row = i * 8 + (lane >> 3);
        int nb = __shfl(myadj, row);
        *reinterpret_cast<u16x8*>(&qs[wv][i * 512 + lane * 8]) =
            *reinterpret_cast<const u16x8*>(qtb + (size_t)nb * 64 + (lane & 7) * 8);
    }
#pragma unroll
    for (int i = 0; i < 4; i++) {
        int row = i * 4 + (lane >> 4);
        int nb = __shfl(myadj, row);
        *reinterpret_cast<u16x8*>(&hs[wv][i * 512 + lane * 8]) =
            *reinterpret_cast<const u16x8*>(hWb + (size_t)nb * 128 + (lane & 15) * 8);
    }
    __syncthreads();

    // lane = hc: neighbor-sum + head-weighted logits + in-register softmax
    {
        float qv[16];
        float s = 0.f;
#pragma unroll
        for (int e = 0; e < 16; e++) { qv[e] = bf2f(qs[wv][e * 64 + lane]); s += qv[e]; }
        float rs = 1.f / s;
        float conv = headConv[lane >> 4];
        float wn[16], m = -1e30f;
#pragma unroll
        for (int e = 0; e < 16; e++) {
            float t = conv * qv[e] * rs;
            t += __shfl_xor(t, 16);
            t += __shfl_xor(t, 32);       // all lanes now hold w_logit[c][e]
            wn[e] = t;
            m = fmaxf(m, t);
        }
        float sum = 0.f;
#pragma unroll
        for (int e = 0; e < 16; e++) { wn[e] = __expf(wn[e] - m); sum += wn[e]; }
        float inv = 1.f / sum;
        const int c = lane & 15, eg = lane >> 4;
#pragma unroll
        for (int j = 0; j < 4; j++) wbuf[wv][eg * 4 + j][c] = wn[eg * 4 + j] * inv;
    }
    __syncthreads();

    // out tile: lane (cg,dg) covers c = cg*4+jc, d = dg*4..+3 and +64..+67
    {
        const int dg = lane & 15, cg = lane >> 4, d0 = dg * 4;
        float bv[8];
        *reinterpret_cast<float4*>(bv)     = *reinterpret_cast<const float4*>(b21 + d0);
        *reinterpret_cast<float4*>(bv + 4) = *reinterpret_cast<const float4*>(b21 + d0 + 64);
        float acc[4][8];
#pragma unroll
        for (int jc = 0; jc < 4; jc++)
#pragma unroll
            for (int j = 0; j < 8; j++) acc[jc][j] = bv[j];

#pragma unroll
        for (int e = 0; e < 16; e++) {
            uint2 wlo = *reinterpret_cast<const uint2*>(&hs[wv][e * 128 + d0]);
            uint2 whi = *reinterpret_cast<const uint2*>(&hs[wv][e * 128 + 64 + d0]);
            float hv[8];
            hv[0] = bflo(wlo.x); hv[1] = bfhi(wlo.x); hv[2] = bflo(wlo.y); hv[3] = bfhi(wlo.y);
            hv[4] = bflo(whi.x); hv[5] = bfhi(whi.x); hv[6] = bflo(whi.y); hv[7] = bfhi(whi.y);
#pragma unroll
            for (int jc = 0; jc < 4; jc++) {
                float w = wbuf[wv][e][cg * 4 + jc];
#pragma unroll
                for (int j = 0; j < 8; j++) acc[jc][j] = fmaf(w, hv[j], acc[jc][j]);
            }
        }
#pragma unroll
        for (int jc = 0; jc < 4; jc++) {
            f32x4 lo, hi;
#pragma unroll
            for (int j = 0; j < 4; j++) { lo[j] = leaky_f(acc[jc][j]); hi[j] = leaky_f(acc[jc][j + 4]); }
            float* dst = out1 + ((size_t)(n * 16 + cg * 4 + jc)) * 128;
            __builtin_nontemporal_store(lo, reinterpret_cast<f32x4*>(dst + d0));
            __builtin_nontemporal_store(hi, reinterpret_cast<f32x4*>(dst + d0 + 64));
        }
    }
}

extern "C" void kernel_launch(void* const* d_in, const int* in_sizes, int n_in,
                              void* d_out, int out_size, void* d_ws, size_t ws_size,
                              hipStream_t stream)
{
    const float* x_node   = (const float*)d_in[0];
    const int*   adj      = (const int*)  d_in[1];
    const float* W1       = (const float*)d_in[3];
    const float* b1       = (const float*)d_in[4];
    const float* W2       = (const float*)d_in[5];
    const float* b2       = (const float*)d_in[6];
    const float* W21      = (const float*)d_in[7];
    const float* b21      = (const float*)d_in[8];
    const float* cent     = (const float*)d_in[9];
    const float* headConv = (const float*)d_in[10];

    const int N = in_sizes[0] / 256;     // 20000

    float* h    = (float*)d_out;                 // h_prime [N][128]
    float* out1 = h + (size_t)N * 128;           // new_feat [N][16][128]

    unsigned short* xb  = (unsigned short*)d_ws;       // [N][256] bf16
    unsigned short* hWb = xb  + (size_t)N * 256;       // [N][128] bf16
    unsigned short* qtb = hWb + (size_t)N * 128;       // [N][64]  bf16
    unsigned short* pw1 = qtb + (size_t)N * 64;        // 32768
    unsigned short* pw2 = pw1 + 32768;                 // 16384
    unsigned short* pw3 = pw2 + 16384;                 // 24576
    float*          cn2g = (float*)(pw3 + 24576);      // [64]

    const int xblocks = (N * 256) / 4096;              // 1250

    pack_kernel<<<37 + xblocks, 256, 0, stream>>>(x_node, W1, W2, W21, cent,
                                                  xb, pw1, pw2, pw3, cn2g, N);
    fused_gemms<<<N / 16, 256, 0, stream>>>(xb, pw1, pw2, pw3, b1, b2, cn2g,
                                            h, hWb, qtb, N);
    agg_kernel<<<N / 4, 256, 0, stream>>>(adj, qtb, hWb, b21, headConv, out1);
}